// Round 11
// baseline (301.422 us; speedup 1.0000x reference)
//
#include <hip/hip_runtime.h>

// RNN: h_t = tanh(x_t * W_ih^T + b_ih + h_{t-1} W_hh^T + b_hh), out = h_T W_fc^T + b_fc
// B=8192, T=784, I=1, H=30 (pad 32), C=10. fp32.
//
// R13 = R12 (two-wave tile split, 1024 waves, parity double-buffer, one
// barrier/step) with the LDS round trip OVERLAPPED. R12 is chain-bound:
// 686 clk/step = issue 283 + exposed 403 (write->barrier->b128 read ~120 +
// MFMA 2L + tanh + pack all serial). Observation: in the R12 layout each
// wave's B fragment is half its OWN h (k-slots j=4wv..4wv+3, in registers
// right after pack) and half the partner's. So each K32 MFMA splits into
// two half-masked MFMAs: own-half issued BEFORE the barrier (no LDS dep),
// partner-half after the read. Post-barrier chain shrinks to read(120) +
// 3 independent MFMAs (exposed ~1L) + 2 vec adds + tanh + pack ~= 400.
// Same products, reassociated sum; 6 MFMAs instead of 3 (free at 7% util).
// Everything else proven in R12: permutation rr=8(n>>2)+(n&3)+4wv, BPAIR
// split-float pack, tanh_e2 with SCL=2*log2e folded into W/bias, parity
// scheme (write p -> barrier -> read p; writes t+1 go to p^1 -> race-free),
// FC head via LDS gather.

#define BB 8192
#define TT 784
#define HH 30
#define CC 10

typedef __attribute__((ext_vector_type(8))) short  bf16x8;
typedef __attribute__((ext_vector_type(4))) float  f32x4;
typedef __attribute__((ext_vector_type(4))) unsigned uint4v;

#if __has_builtin(__builtin_amdgcn_exp2f)
#define EXP2(v) __builtin_amdgcn_exp2f(v)
#else
#define EXP2(v) __expf((v) * 0.69314718055994531f)   // e^(x ln2) = 2^x
#endif

// pre-scale folded into W_hh/W_ih/bias: 2*log2(e)
#define SCL 2.8853900817779268f

__device__ __forceinline__ float tanh_e2(float s) {
    // s = 2*log2e*a ;  tanh(a) = 1 - 2/(2^s + 1)
    return 1.0f - 2.0f * __builtin_amdgcn_rcpf(EXP2(s) + 1.0f);
}

// (p0,p1) f32 -> packed bf16 pair hp (hi) + packed bf16 residual pair lp.
#define BPAIR(p0, p1, hp, lp) do {                                          \
    asm("v_cvt_pk_bf16_f32 %0, %1, %2" : "=v"(hp) : "v"(p0), "v"(p1));      \
    const float _h0 = __uint_as_float((hp) << 16);                          \
    const float _h1 = __uint_as_float((hp) & 0xffff0000u);                  \
    const float _l0 = (p0) - _h0;                                           \
    const float _l1 = (p1) - _h1;                                           \
    asm("v_cvt_pk_bf16_f32 %0, %1, %2" : "=v"(lp) : "v"(_l0), "v"(_l1));    \
} while (0)

#define MFMA(A, B, C) __builtin_amdgcn_mfma_f32_16x16x32_bf16((A), (B), (C), 0, 0, 0)

__global__ __launch_bounds__(128)
__attribute__((amdgpu_waves_per_eu(1, 1)))
void rnn_scan_kernel(const float* __restrict__ x,
                     const float* __restrict__ W_ih,
                     const float* __restrict__ W_hh,
                     const float* __restrict__ b_ih,
                     const float* __restrict__ b_hh,
                     const float* __restrict__ W_fc,
                     const float* __restrict__ b_fc,
                     float* __restrict__ out) {
    // E[parity][wv][lane] = this wave's packed own-half {hp0,hp1,lp0,lp1}.
    __shared__ uint4v E[2][2][64];
    __shared__ float hfc[16][33];

    const int tid  = threadIdx.x;
    const int wv   = tid >> 6;        // 0: rows j=0..3 slots, 1: rows j=4..7
    const int lane = tid & 63;
    const int n    = lane & 15;       // batch column / A-tile row
    const int g    = lane >> 4;       // k-group / D-row group
    const int b    = blockIdx.x * 16 + n;

    // ---- A fragment (R12-proven permutation; full K=32 per wave) ----
    const int rr = 8 * (n >> 2) + (n & 3) + 4 * wv;   // 30,31 -> zero rows
    unsigned ah[4], al[4];
#pragma unroll
    for (int d = 0; d < 4; ++d) {
        const int k0 = 8 * g + 2 * d, k1 = k0 + 1;
        const float wa = (rr < HH && k0 < HH) ? SCL * W_hh[rr * HH + k0] : 0.f;
        const float wb = (rr < HH && k1 < HH) ? SCL * W_hh[rr * HH + k1] : 0.f;
        const unsigned ua = __float_as_uint(wa), ub = __float_as_uint(wb);
        ah[d] = (ub & 0xffff0000u) | (ua >> 16);
        const float la = wa - __uint_as_float(ua & 0xffff0000u);
        const float lb = wb - __uint_as_float(ub & 0xffff0000u);
        al[d] = (__float_as_uint(lb) & 0xffff0000u) | (__float_as_uint(la) >> 16);
    }
    bf16x8 Ah = __builtin_bit_cast(bf16x8, (uint4v){ah[0], ah[1], ah[2], ah[3]});
    bf16x8 Al = __builtin_bit_cast(bf16x8, (uint4v){al[0], al[1], al[2], al[3]});
    asm volatile("" : "+v"(Ah), "+v"(Al));

    // ---- C-init params: this lane+wave's D rows are h rows 8g+4wv+r ----
    float bias[4], wih[4];
#pragma unroll
    for (int r = 0; r < 4; ++r) {
        const int q = 8 * g + 4 * wv + r;             // 30,31 -> zero
        bias[r] = (q < HH) ? SCL * (b_ih[q] + b_hh[q]) : 0.f;
        wih[r]  = (q < HH) ? SCL * W_ih[q] : 0.f;
        asm volatile("" : "+v"(bias[r]), "+v"(wih[r]));
    }

    // own h state (4 rows); rows 30/31: acc==0 -> tanh_e2(0)=0 exactly.
    float h0 = 0.f, h1 = 0.f, h2 = 0.f, h3 = 0.f;

    const float* xp = x + (size_t)b * TT;
    const int NQ = TT / 4;
    float4 xq = *(const float4*)xp;
    float4 xn = *(const float4*)(xp + 4);

    for (int qq = 0; qq < NQ; ++qq) {
        const float4 xf = (qq + 2 < NQ) ? *(const float4*)(xp + (qq + 2) * 4)
                                        : make_float4(0.f, 0.f, 0.f, 0.f);
#pragma unroll
        for (int u = 0; u < 4; ++u) {
            const float xt = (u == 0) ? xq.x : (u == 1) ? xq.y
                           : (u == 2) ? xq.z : xq.w;
            const int p = u & 1;   // step parity (t = 4qq+u, t&1 == u&1)

            // 1. pack own h(t-1), publish 16B
            unsigned hp0, hp1, lp0, lp1;
            BPAIR(h0, h1, hp0, lp0);
            BPAIR(h2, h3, hp1, lp1);
            E[p][wv][lane] = (uint4v){hp0, hp1, lp0, lp1};

            // 2. own-half B fragments (own k-slots = words 2wv, 2wv+1)
            uint4v bh, bl;
            if (wv == 0) { bh = (uint4v){hp0, hp1, 0, 0}; bl = (uint4v){lp0, lp1, 0, 0}; }
            else         { bh = (uint4v){0, 0, hp0, hp1}; bl = (uint4v){0, 0, lp0, lp1}; }
            const bf16x8 Bh = __builtin_bit_cast(bf16x8, bh);
            const bf16x8 Bl = __builtin_bit_cast(bf16x8, bl);

            // 3. C-init + own-half MFMAs (no LDS dependency -> pre-barrier)
            f32x4 acc = { fmaf(xt, wih[0], bias[0]), fmaf(xt, wih[1], bias[1]),
                          fmaf(xt, wih[2], bias[2]), fmaf(xt, wih[3], bias[3]) };
            const f32x4 zed = {0.f, 0.f, 0.f, 0.f};
            f32x4 P0 = MFMA(Ah, Bh, acc);
            f32x4 Q0 = MFMA(Ah, Bl, zed);
            Q0 = MFMA(Al, Bh, Q0);

            // 4. exchange
            __syncthreads();
            const uint4v rv = E[p][wv ^ 1][lane];
            const unsigned r0 = rv[0], r1 = rv[1], r2 = rv[2], r3 = rv[3];
            uint4v ch, cl;
            if (wv == 0) { ch = (uint4v){0, 0, r0, r1}; cl = (uint4v){0, 0, r2, r3}; }
            else         { ch = (uint4v){r0, r1, 0, 0}; cl = (uint4v){r2, r3, 0, 0}; }
            const bf16x8 Ch = __builtin_bit_cast(bf16x8, ch);
            const bf16x8 Cl = __builtin_bit_cast(bf16x8, cl);

            // 5. partner-half MFMAs: three independent chains, exposed ~1L
            const f32x4 d1 = MFMA(Ah, Ch, P0);
            const f32x4 d2 = MFMA(Ah, Cl, Q0);
            const f32x4 d3 = MFMA(Al, Ch, zed);
            const f32x4 s  = (d1 + d2) + d3;

            // 6. tanh (input pre-scaled by SCL)
            h0 = tanh_e2(s[0]); h1 = tanh_e2(s[1]);
            h2 = tanh_e2(s[2]); h3 = tanh_e2(s[3]);
        }
        xq = xn;
        xn = xf;
    }

    // ---- FC head: gather full h per batch in LDS, wave 0 computes ----
    hfc[n][8 * g + 4 * wv + 0] = h0;
    hfc[n][8 * g + 4 * wv + 1] = h1;
    hfc[n][8 * g + 4 * wv + 2] = h2;
    hfc[n][8 * g + 4 * wv + 3] = h3;
    __syncthreads();
    if (wv == 0) {
#pragma unroll
        for (int j = 0; j < 3; ++j) {
            const int c = g + 4 * j;          // covers c=0..9 exactly once
            if (c < CC) {
                float acc = b_fc[c];
#pragma unroll
                for (int k = 0; k < HH; ++k)
                    acc = fmaf(W_fc[c * HH + k], hfc[n][k], acc);
                out[(size_t)b * CC + c] = acc;
            }
        }
    }
}

extern "C" void kernel_launch(void* const* d_in, const int* in_sizes, int n_in,
                              void* d_out, int out_size, void* d_ws, size_t ws_size,
                              hipStream_t stream) {
    const float* x    = (const float*)d_in[0];
    const float* W_ih = (const float*)d_in[1];
    const float* W_hh = (const float*)d_in[2];
    const float* b_ih = (const float*)d_in[3];
    const float* b_hh = (const float*)d_in[4];
    const float* W_fc = (const float*)d_in[5];
    const float* b_fc = (const float*)d_in[6];

    hipLaunchKernelGGL(rnn_scan_kernel,
                       dim3(BB / 16), dim3(128), 0, stream,
                       x, W_ih, W_hh, b_ih, b_hh, W_fc, b_fc,
                       (float*)d_out);
}